// Round 6
// baseline (442.695 us; speedup 1.0000x reference)
//
#include <hip/hip_runtime.h>
#include <hip/hip_bf16.h>

typedef float f32x4 __attribute__((ext_vector_type(4)));
typedef __bf16 bf16x8v __attribute__((ext_vector_type(8)));
typedef __bf16 bf16x4v __attribute__((ext_vector_type(4)));
typedef unsigned uint2v __attribute__((ext_vector_type(2)));
typedef bf16x8v __attribute__((may_alias)) bf16x8;
typedef bf16x4v __attribute__((may_alias)) bf16x4;
typedef uint2v __attribute__((may_alias)) u32x2;

typedef __attribute__((address_space(1))) const void gvoid_t;
typedef __attribute__((address_space(3))) void lvoid_t;

#define DEVINL __device__ __forceinline__

#define BDIM 2
#define TDIM 2048
#define CDIM 2048
#define NHEAD 16
#define DHEAD 128
#define MROWS 4096
#define WSZ ((size_t)CDIM * CDIM)
#define XSZ ((size_t)MROWS * CDIM)

// barrier without the compiler's conservative vmcnt(0) drain: LDS ops are
// flushed (lgkmcnt), in-flight global prefetch loads stay in flight.
// (attn kernel: proven form, left untouched)
#define BARRIER_LGKM() asm volatile("s_waitcnt lgkmcnt(0)\ns_barrier" ::: "memory")

DEVINL __bf16 f2bf(float f) {
  unsigned u = __builtin_bit_cast(unsigned, f);
  u += 0x7fffu + ((u >> 16) & 1u);  // RNE
  unsigned short h = (unsigned short)(u >> 16);
  return __builtin_bit_cast(__bf16, h);
}

// pack two f32 -> two bf16 (truncation) in one v_perm
DEVINL unsigned pk2bf_trunc(float lo, float hi) {
  return __builtin_amdgcn_perm(__builtin_bit_cast(unsigned, hi),
                               __builtin_bit_cast(unsigned, lo), 0x07060302);
}

DEVINL void gl2lds16(const void* g, void* l) {
  __builtin_amdgcn_global_load_lds((gvoid_t*)g, (lvoid_t*)l, 16, 0, 0);
}

// ---------------------------------------------------------------------------
// dtype probe (bf16 vs f32) + zero the attn work-stealing counter.
__global__ void detect_dtype(const unsigned* __restrict__ w,
                             int* __restrict__ flag, int* __restrict__ cnt) {
  const int l = threadIdx.x;  // 64 threads
  if (l == 0) *cnt = 0;
  const unsigned word = w[l];
  const unsigned e = (word >> 7) & 0xFFu;
  const int vote = (e >= 0x70u && e <= 0x87u) ? 1 : 0;
  const unsigned long long m = __ballot(vote);
  if (l == 0) *flag = (__popcll(m) >= 32) ? 1 : 0;
}

// ---------------------------------------------------------------------------
__global__ __launch_bounds__(256) void cvt_src(const void* __restrict__ in,
                                               __bf16* __restrict__ out,
                                               const int* __restrict__ flag,
                                               int n8) {
  const int i = blockIdx.x * 256 + threadIdx.x;
  if (i >= n8) return;
  if (*flag) {
    ((bf16x8*)out)[i] = ((const bf16x8*)in)[i];
  } else {
    const float* f = (const float*)in + (size_t)i * 8;
    bf16x8v v;
#pragma unroll
    for (int j = 0; j < 8; ++j) v[j] = f2bf(f[j]);
    ((bf16x8*)out)[i] = v;
  }
}

// ---------------------------------------------------------------------------
__global__ __launch_bounds__(256) void cvt_wt(
    const void* __restrict__ w0, const void* __restrict__ w1,
    const void* __restrict__ w2, const void* __restrict__ w3,
    __bf16* __restrict__ out, const int* __restrict__ flag) {
  __shared__ __attribute__((aligned(16))) __bf16 tile[64][68];
  const void* W = (blockIdx.z == 0) ? w0 : (blockIdx.z == 1) ? w1
                : (blockIdx.z == 2) ? w2 : w3;
  __bf16* Wt = out + (size_t)blockIdx.z * WSZ;
  const int tx = threadIdx.x & 63, ty = threadIdx.x >> 6;
  const int k0 = blockIdx.x * 64, n0 = blockIdx.y * 64;
  const int fl = *flag;
#pragma unroll
  for (int i = ty; i < 64; i += 4) {
    const size_t off = (size_t)(k0 + i) * CDIM + n0 + tx;
    const float v = fl ? (float)((const __bf16*)W)[off] : ((const float*)W)[off];
    tile[i][tx] = f2bf(v);
  }
  __syncthreads();
#pragma unroll
  for (int i = ty; i < 64; i += 4)
    Wt[(size_t)(n0 + i) * CDIM + k0 + tx] = tile[tx][i];
}

// ---------------------------------------------------------------------------
__global__ __launch_bounds__(256) void cvt_bias(
    const void* __restrict__ b0, const void* __restrict__ b1,
    const void* __restrict__ b2, const void* __restrict__ b3,
    float* __restrict__ out, const int* __restrict__ flag) {
  const int i = blockIdx.x * 256 + threadIdx.x;  // 0..8191
  const void* b = (i < 2048) ? b0 : (i < 4096) ? b1 : (i < 6144) ? b2 : b3;
  const int idx = i & 2047;
  out[i] = (*flag) ? (float)((const __bf16*)b)[idx] : ((const float*)b)[idx];
}

// ---------------------------------------------------------------------------
// The m201 combination, assembled for the first time (R4 had the geometry
// with drain-0; R5 had counted-vmcnt with halved wave tiles; m218 A/B says
// the PAIR is the +38-73% lever).  BM=256, BN=256(QKV)/128(out), BK=64 as
// two K=32 halves; 512 thr = 8 waves; per-wave 128x64 (MODE0, 2Mx4N) or
// 64x64 (MODE1, 4Mx2N).  Half h=2*kt+ks lives in ring slot h&3 per operand
// (A slot 256x32=16KB, x4; B slot BNx32, x4; LDS 128/96 KiB).
// Phases per K-tile (MODE0: 4 = m-half x ks; MODE1: 2 = ks):
//   { ds_read frags | stage one A- or B-part of a future half (2/1 gl2lds)
//     -> s_barrier -> lgkmcnt(0)+sched_barrier
//     -> setprio(1) 16 MFMA setprio(0) -> [vmcnt(N)] -> s_barrier }
// Ledger (per-wave, MODE0, 2 A-loads + 2 B-loads per half):
//   prologue: halves 0,1 (8 loads); vmcnt(4) certifies h0.
//   tile kt stages h=2kt+2 (A@P1, B@P2) and h=2kt+3 (A@P3, B@P4).
//   P2-end vmcnt(4): outstanding = P3P4(kt-1)+P1P2(kt) = 8 -> certifies
//     h 2kt+1 (needed at P3).  P4-end vmcnt(4): outstanding = P1..P4 = 8 ->
//     certifies h 2kt+2 (needed at next P1).  Never 0 until kt=NKT-1.
//   Flight time 2-3 phases (~600-1200 cyc) >= HBM ~900 cyc.
// Ring slots make read/write LDS regions disjoint ((h+2)&3 != h&3, (h+3)&3
// != (h+1)&3), so staging never targets a slot being read this tile.
// LDS pair-line layout + involution = R5's functionally-verified math:
// line L=row>>1, slot s=(row&1)*4+k8, phys=s^(L&7); gl2lds dest linear,
// source pre-swizzled (ls/rbase/cb8), reads use lane_e = L2*64+physr*8.
template <int MODE>
__global__ __launch_bounds__(512, 2) void gemm8p(
    const __bf16* __restrict__ A, const __bf16* __restrict__ Bt,
    const float* __restrict__ bias, __bf16* __restrict__ qb,
    __bf16* __restrict__ kb, __bf16* __restrict__ vtb,
    const int* __restrict__ flag, void* __restrict__ outp) {
  constexpr int K = CDIM;
  constexpr int NKT = K / 64;                  // 32 K-tiles, 64 halves
  constexpr int BN = (MODE == 0) ? 256 : 128;  // tile N
  constexpr int WMR = (MODE == 0) ? 128 : 64;  // per-wave M rows
  constexpr int MF = WMR / 16;                 // 8 or 4 A-frags
  constexpr int BLD = BN / 128;                // B loads per stage-part: 2/1
  __shared__ __attribute__((aligned(16))) __bf16 Asl[4][256 * 32];
  __shared__ __attribute__((aligned(16))) __bf16 Bsl[4][BN * 32];

  const int tid = threadIdx.x;
  const int w = tid >> 6, l = tid & 63;
  const int quad = l >> 4, l16 = l & 15;
  const int wm = (MODE == 0) ? (w >> 2) : (w >> 1);
  const int wn = (MODE == 0) ? (w & 3) : (w & 1);

  const int bid = blockIdx.x;
  const int bm = bid & 15, bn = bid >> 4;  // bm-fastest: B panel L2-shared
  const int m0 = bm * 256, n0 = bn * BN;

  // staging source pre-swizzle (R5-verified): dest element e*4096+tid*8 ->
  // line L=e*64+(tid>>3), phys=tid&7 -> logical slot ls=phys^(L&7) ->
  // row = e*128 + 2*(tid>>3) + (ls>>2), k8 = ls&3.
  const int ls = (tid & 7) ^ ((tid >> 3) & 7);
  const int rbase = 2 * (tid >> 3) + (ls >> 2);  // 0..127
  const int cb8e = (ls & 3) * 8;
  const __bf16* gA = A + (size_t)(m0 + rbase) * K + cb8e;
  const __bf16* gB = Bt + (size_t)(n0 + rbase) * K + cb8e;

  // fragment read addressing: row = base + l16 -> L2 = l16>>1,
  // physr = (((l16&1)<<2)+quad)^L2, element = (line)*64 + physr*8.
  const int L2 = l16 >> 1;
  const int physr = ((((l16 & 1) << 2) + quad) ^ L2) & 7;
  const int lane_e = L2 * 64 + physr * 8;
  const int abase = wm * WMR * 32;  // wave's A line block
  const int bbase = wn * 2048;      // wave's B line block (64 N-rows)

  f32x4 acc[MF][4];
#pragma unroll
  for (int i = 0; i < MF; ++i)
#pragma unroll
    for (int j = 0; j < 4; ++j) acc[i][j] = (f32x4){0.f, 0.f, 0.f, 0.f};

#define STAGE_A(h)                                                           \
  {                                                                          \
    const int _s = (h) & 3;                                                  \
    const size_t _c = (size_t)((h) >> 1) * 64 + ((h) & 1) * 32;              \
    gl2lds16(gA + _c, (__bf16*)Asl[_s] + w * 512);                           \
    gl2lds16(gA + (size_t)128 * K + _c, (__bf16*)Asl[_s] + 4096 + w * 512);  \
  }
#define STAGE_B(h)                                                           \
  {                                                                          \
    const int _s = (h) & 3;                                                  \
    const size_t _c = (size_t)((h) >> 1) * 64 + ((h) & 1) * 32;              \
    gl2lds16(gB + _c, (__bf16*)Bsl[_s] + w * 512);                           \
    if (BLD == 2)                                                            \
      gl2lds16(gB + (size_t)128 * K + _c, (__bf16*)Bsl[_s] + 4096 + w * 512); \
  }
#define DS_FRAGS(AP, BP, MI0, DO_B)                                          \
  _Pragma("unroll") for (int i = 0; i < 4; ++i)                              \
      afr[i] = *(const bf16x8*)&(AP)[abase + ((MI0) + i) * 512 + lane_e];    \
  if (DO_B) {                                                                \
    _Pragma("unroll") for (int nf = 0; nf < 4; ++nf)                         \
        bfr[nf] = *(const bf16x8*)&(BP)[bbase + nf * 512 + lane_e];          \
  }
#define MFMA16(MI0)                                                          \
  __builtin_amdgcn_s_setprio(1);                                             \
  _Pragma("unroll") for (int i = 0; i < 4; ++i)                              \
      _Pragma("unroll") for (int nf = 0; nf < 4; ++nf)                       \
          acc[(MI0) + i][nf] = __builtin_amdgcn_mfma_f32_16x16x32_bf16(      \
              afr[i], bfr[nf], acc[(MI0) + i][nf], 0, 0, 0);                 \
  __builtin_amdgcn_s_setprio(0);
#define LGKM0()                                                              \
  asm volatile("s_waitcnt lgkmcnt(0)" ::: "memory");                         \
  __builtin_amdgcn_sched_barrier(0)
#define VM_N()                                                               \
  do {                                                                       \
    if constexpr (MODE == 0)                                                 \
      asm volatile("s_waitcnt vmcnt(4)" ::: "memory");                       \
    else                                                                     \
      asm volatile("s_waitcnt vmcnt(3)" ::: "memory");                       \
    __builtin_amdgcn_sched_barrier(0);                                       \
  } while (0)
#define VM_0()                                                               \
  do {                                                                       \
    asm volatile("s_waitcnt vmcnt(0)" ::: "memory");                         \
    __builtin_amdgcn_sched_barrier(0);                                       \
  } while (0)

  // prologue: halves 0 and 1; certify half 0 (leave half 1 in flight).
  STAGE_A(0) STAGE_B(0) STAGE_A(1) STAGE_B(1)
  VM_N();
  __builtin_amdgcn_s_barrier();

  for (int kt = 0; kt < NKT; ++kt) {
    const __bf16* A0 = Asl[(2 * kt) & 3];
    const __bf16* B0 = Bsl[(2 * kt) & 3];
    const __bf16* A1 = Asl[(2 * kt + 1) & 3];
    const __bf16* B1 = Bsl[(2 * kt + 1) & 3];
    const bool st = (kt + 1 < NKT);
    bf16x8 afr[4], bfr[4];

    if (MODE == 0) {
      // ---- P1 (ks0, mi0-3): 8 ds_reads; stage A-part of half 2kt+2
      DS_FRAGS(A0, B0, 0, 1)
      if (st) STAGE_A(2 * kt + 2)
      __builtin_amdgcn_s_barrier();
      LGKM0();
      MFMA16(0)
      __builtin_amdgcn_s_barrier();

      // ---- P2 (ks0, mi4-7): 4 ds_reads; stage B-part of half 2kt+2
      DS_FRAGS(A0, B0, 4, 0)
      if (st) STAGE_B(2 * kt + 2)
      __builtin_amdgcn_s_barrier();
      LGKM0();
      MFMA16(4)
      if (st) VM_N(); else VM_0();  // certify half 2kt+1 (read in P3)
      __builtin_amdgcn_s_barrier();

      // ---- P3 (ks1, mi0-3): 8 ds_reads; stage A-part of half 2kt+3
      DS_FRAGS(A1, B1, 0, 1)
      if (st) STAGE_A(2 * kt + 3)
      __builtin_amdgcn_s_barrier();
      LGKM0();
      MFMA16(0)
      __builtin_amdgcn_s_barrier();

      // ---- P4 (ks1, mi4-7): 4 ds_reads; stage B-part of half 2kt+3
      DS_FRAGS(A1, B1, 4, 0)
      if (st) STAGE_B(2 * kt + 3)
      __builtin_amdgcn_s_barrier();
      LGKM0();
      MFMA16(4)
      if (st) VM_N();  // certify half 2kt+2 (read at next P1)
      __builtin_amdgcn_s_barrier();
    } else {
      // ---- P1 (ks0): 8 ds_reads; stage half 2kt+2 (A+B, 3 loads)
      DS_FRAGS(A0, B0, 0, 1)
      if (st) { STAGE_A(2 * kt + 2) STAGE_B(2 * kt + 2) }
      __builtin_amdgcn_s_barrier();
      LGKM0();
      MFMA16(0)
      if (st) VM_N(); else VM_0();  // certify half 2kt+1 (read in P2)
      __builtin_amdgcn_s_barrier();

      // ---- P2 (ks1): stage half 2kt+3
      DS_FRAGS(A1, B1, 0, 1)
      if (st) { STAGE_A(2 * kt + 3) STAGE_B(2 * kt + 3) }
      __builtin_amdgcn_s_barrier();
      LGKM0();
      MFMA16(0)
      if (st) VM_N();  // certify half 2kt+2
      __builtin_amdgcn_s_barrier();
    }
  }
#undef STAGE_A
#undef STAGE_B
#undef DS_FRAGS
#undef MFMA16
#undef LGKM0
#undef VM_N
#undef VM_0

  if (MODE == 0) {
    // QKV scatter (R4-verified): Q,K -> [b,h,t,d]; V -> [b,h,d,t] (bf16x4).
    const int mat = n0 >> 11;  // 0=Q 1=K 2=V (BN=256 divides 2048)
#pragma unroll
    for (int nf = 0; nf < 4; ++nf) {
      const int n = n0 + wn * 64 + nf * 16 + l16;  // 0..6143
      const int nn = n & 2047;
      const int h = nn >> 7, d = nn & 127;
      const float bv = bias[n];
#pragma unroll
      for (int mi = 0; mi < MF; ++mi) {
        const int mbase = m0 + wm * WMR + mi * 16 + quad * 4;
        const int bb = mbase >> 11, t = mbase & 2047;
        if (mat == 2) {
          bf16x4v v4;
#pragma unroll
          for (int r = 0; r < 4; ++r) v4[r] = f2bf(acc[mi][nf][r] + bv);
          *(bf16x4*)&vtb[((size_t)(bb * NHEAD + h) * DHEAD + d) * TDIM + t] = v4;
        } else {
          __bf16* op = (mat == 0) ? qb : kb;
#pragma unroll
          for (int r = 0; r < 4; ++r)
            op[((size_t)(bb * NHEAD + h) * TDIM + t + r) * DHEAD + d] =
                f2bf(acc[mi][nf][r] + bv);
        }
      }
    }
  } else {
    const int ofl = *flag;
#pragma unroll
    for (int nf = 0; nf < 4; ++nf) {
      const int n = n0 + wn * 64 + nf * 16 + l16;
      const float bv = bias[n];
#pragma unroll
      for (int mi = 0; mi < MF; ++mi) {
#pragma unroll
        for (int r = 0; r < 4; ++r) {
          const int m = m0 + wm * WMR + mi * 16 + quad * 4 + r;
          const float v = acc[mi][nf][r] + bv;
          if (ofl) ((__bf16*)outp)[(size_t)m * CDIM + n] = f2bf(v);
          else     ((float*)outp)[(size_t)m * CDIM + n] = v;
        }
      }
    }
  }
}

// ---------------------------------------------------------------------------
// Flash-style causal attention (R3 structure, proven 124 us): persistent
// blocks + work-stealing, LDS-staged K/V, 2 lgkm-only barriers per s-block,
// register-double-buffered staging. (256,2): kernel needs ~180 regs/wave —
// forcing 3 waves/EU spills to scratch (R5: 228 MB writes, 3x slower).
__global__ __launch_bounds__(256, 2) void attn(
    const __bf16* __restrict__ Q, const __bf16* __restrict__ K,
    const __bf16* __restrict__ Vt, __bf16* __restrict__ ctx,
    int* __restrict__ cnt) {
  constexpr float CSC = 0.12753139726f;  // log2(e)/sqrt(128)
  __shared__ __attribute__((aligned(16))) __bf16 Kls[64 * 128];   // [s][d]
  __shared__ __attribute__((aligned(16))) __bf16 Vls[128 * 64];   // [d][s]
  __shared__ __attribute__((aligned(16))) __bf16 Pls[4][32 * 64]; // [t][s]
  __shared__ int jobLds;

  const int tid = threadIdx.x;
  const int w = tid >> 6, l = tid & 63, quad = l >> 4, l16 = l & 15;

  const int krow = tid >> 4;                 // 0..15, +16 per pass
  const int kcol = tid & 15;
  const int kldsoff = ((kcol ^ krow) * 8);
  const int vrow = tid >> 3;                 // 0..31, +32 per pass
  const int vcol = tid & 7;
  const int vldsoff = ((vcol ^ (vrow & 7)) * 8);

  for (;;) {
    __syncthreads();
    if (tid == 0) jobLds = atomicAdd(cnt, 1);
    __syncthreads();
    const int j = jobLds;
    if (j >= 512) break;
    const int qt = 15 - (j >> 5);   // all qt=15 jobs first (LPT)
    const int bh = j & 31;
    const int t0w = qt * 128 + w * 32;
    const __bf16* Qbh = Q + (size_t)bh * TDIM * DHEAD;
    const __bf16* Kbh = K + (size_t)bh * TDIM * DHEAD;
    const __bf16* Vbh = Vt + (size_t)bh * TDIM * DHEAD;

    bf16x8 qf[2][4];
#pragma unroll
    for (int tt = 0; tt < 2; ++tt)
#pragma unroll
      for (int ks = 0; ks < 4; ++ks)
        qf[tt][ks] = *(const bf16x8*)(Qbh +
                     (size_t)(t0w + tt * 16 + l16) * DHEAD + ks * 32 + quad * 8);

    f32x4 oacc[8][2];
#pragma unroll
    for (int dt = 0; dt < 8; ++dt)
#pragma unroll
      for (int tt = 0; tt < 2; ++tt) oacc[dt][tt] = (f32x4){0.f, 0.f, 0.f, 0.f};
    float mrow[2] = {-1e30f, -1e30f};
    float lrow[2] = {0.f, 0.f};

    const int nsb = 2 * (qt + 1);

    // prefetch s-block 0 into regs
    bf16x8 kr[4], vr[4];
#pragma unroll
    for (int p = 0; p < 4; ++p)
      kr[p] = *(const bf16x8*)(Kbh + (size_t)(p * 16 + krow) * DHEAD + kcol * 8);
#pragma unroll
    for (int p = 0; p < 4; ++p)
      vr[p] = *(const bf16x8*)(Vbh + (size_t)(p * 32 + vrow) * TDIM + vcol * 8);

    for (int sb = 0; sb < nsb; ++sb) {
      const int s0 = sb * 64;
      BARRIER_LGKM();  // prior iteration's LDS reads complete
#pragma unroll
      for (int p = 0; p < 4; ++p)
        *(bf16x8*)&Kls[(p * 16 + krow) * 128 + kldsoff] = kr[p];
#pragma unroll
      for (int p = 0; p < 4; ++p)
        *(bf16x8*)&Vls[(p * 32 + vrow) * 64 + vldsoff] = vr[p];
      if (sb + 1 < nsb) {
        const int s1 = s0 + 64;
#pragma unroll
        for (int p = 0; p < 4; ++p)
          kr[p] = *(const bf16x8*)(Kbh + (size_t)(s1 + p * 16 + krow) * DHEAD +
                                   kcol * 8);
#pragma unroll
        for (int p = 0; p < 4; ++p)
          vr[p] = *(const bf16x8*)(Vbh + (size_t)(p * 32 + vrow) * TDIM + s1 +
                                   vcol * 8);
      }
      BARRIER_LGKM();  // staging visible; prefetch loads remain in flight
      if (s0 > t0w + 31) continue;  // fully masked for this wave

      // S^T = K.Q^T : D[row=s: quad*4+r][col=t: l16]
      f32x4 sacc[4][2];
#pragma unroll
      for (int st = 0; st < 4; ++st)
#pragma unroll
        for (int tt = 0; tt < 2; ++tt) sacc[st][tt] = (f32x4){0.f, 0.f, 0.f, 0.f};
#pragma unroll
      for (int ks = 0; ks < 4; ++ks) {
        bf16x8 kf[4];
#pragma unroll
        for (int st = 0; st < 4; ++st)
          kf[st] = *(const bf16x8*)&Kls[(st * 16 + l16) * 128 +
                                        (((ks * 4 + quad) ^ l16) * 8)];
#pragma unroll
        for (int st = 0; st < 4; ++st)
#pragma unroll
          for (int tt = 0; tt < 2; ++tt)
            sacc[st][tt] = __builtin_amdgcn_mfma_f32_16x16x32_bf16(
                kf[st], qf[tt][ks], sacc[st][tt], 0, 0, 0);
      }
      if (s0 + 63 > t0w) {  // causal mask near diagonal
#pragma unroll
        for (int st = 0; st < 4; ++st)
#pragma unroll
          for (int tt = 0; tt < 2; ++tt)
#pragma unroll
            for (int r = 0; r < 4; ++r) {
              const int s = s0 + st * 16 + quad * 4 + r;
              const int t = t0w + tt * 16 + l16;
              if (s > t) sacc[st][tt][r] = -1e30f;
            }
      }
      // online softmax per t-column
#pragma unroll
      for (int tt = 0; tt < 2; ++tt) {
        float vm = -1e30f;
#pragma unroll
        for (int st = 0; st < 4; ++st)
#pragma unroll
          for (int r = 0; r < 4; ++r) vm = fmaxf(vm, sacc[st][tt][r]);
        vm = fmaxf(vm, __shfl_xor(vm, 16));
        vm = fmaxf(vm, __shfl_xor(vm, 32));
        const float mnew = fmaxf(mrow[tt], vm);
        // skip the 64-mul rescale when no lane's max grew
        if (__ballot(mnew > mrow[tt])) {
          const float alpha = exp2f((mrow[tt] - mnew) * CSC);
          lrow[tt] *= alpha;
#pragma unroll
          for (int dt = 0; dt < 8; ++dt)
#pragma unroll
            for (int r = 0; r < 4; ++r) oacc[dt][tt][r] *= alpha;
          mrow[tt] = mnew;
        }
        float rs = 0.f;
#pragma unroll
        for (int st = 0; st < 4; ++st) {
          const float p0 = exp2f((sacc[st][tt][0] - mnew) * CSC);
          const float p1 = exp2f((sacc[st][tt][1] - mnew) * CSC);
          const float p2 = exp2f((sacc[st][tt][2] - mnew) * CSC);
          const float p3 = exp2f((sacc[st][tt][3] - mnew) * CSC);
          rs += (p0 + p1) + (p2 + p3);
          u32x2 pk = {pk2bf_trunc(p0, p1), pk2bf_trunc(p2, p3)};
          *(u32x2*)&Pls[w][(tt * 16 + l16) * 64 +
                           (((st * 2 + (quad >> 1)) ^ (l16 & 7)) * 8) +
                           (quad & 1) * 4] = pk;
        }
        rs += __shfl_xor(rs, 16);
        rs += __shfl_xor(rs, 32);
        lrow[tt] += rs;
      }
      // intra-wave P write->read ordering (wave-private region, no barrier)
      asm volatile("s_waitcnt lgkmcnt(0)" ::: "memory");
      // O^T += V^T.P^T : D[row=d][col=t]
#pragma unroll
      for (int ks = 0; ks < 2; ++ks) {
        bf16x8 pf[2];
#pragma unroll
        for (int tt = 0; tt < 2; ++tt)
          pf[tt] = *(const bf16x8*)&Pls[w][(tt * 16 + l16) * 64 +
                                           (((ks * 4 + quad) ^ (l16 & 7)) * 8)];
#pragma unroll
        for (int dt = 0; dt < 8; ++dt) {
          const bf16x8 vf =
              *(const bf16x8*)&Vls[(dt * 16 + l16) * 64 +
                                   (((ks * 4 + quad) ^ (l16 & 7)) * 8)];
#pragma unroll
          for (int tt = 0; tt < 2; ++tt)
            oacc[dt][tt] = __builtin_amdgcn_mfma_f32_16x16x32_bf16(
                vf, pf[tt], oacc[dt][tt], 0, 0, 0);
        }
      }
    }

    // epilogue: O^T[d][t]/l -> ctx[b][t][h*128+d], bf16x4 stores
    const int b = bh >> 4, h = bh & 15;
#pragma unroll
    for (int tt = 0; tt < 2; ++tt) {
      const float rinv = 1.0f / lrow[tt];
      const int t = t0w + tt * 16 + l16;
      __bf16* cp = ctx + ((size_t)(b * TDIM + t)) * CDIM + h * DHEAD;
#pragma unroll
      for (int dt = 0; dt < 8; ++dt) {
        bf16x4v v4;
#pragma unroll
        for (int r = 0; r < 4; ++r) v4[r] = f2bf(oacc[dt][tt][r] * rinv);
        *(bf16x4*)&cp[dt * 16 + quad * 4] = v4;
      }
    }
  }
}

// ---------------------------------------------------------------------------
extern "C" void kernel_launch(void* const* d_in, const int* in_sizes, int n_in,
                              void* d_out, int out_size, void* d_ws,
                              size_t ws_size, hipStream_t stream) {
  const void* src = d_in[0];
  const void* Wq = d_in[1];
  const void* bq = d_in[2];
  const void* Wk = d_in[3];
  const void* bk = d_in[4];
  const void* Wv = d_in[5];
  const void* bv = d_in[6];
  const void* Wo = d_in[7];
  const void* bo = d_in[8];

  char* wsb = (char*)d_ws;
  int* flag = (int*)wsb;                  // +0
  int* cnt = (int*)(wsb + 128);           // +128 (work-steal counter)
  __bf16* srcbf = (__bf16*)(wsb + 256);
  __bf16* wqt = srcbf + XSZ;              // q,k,v,o transposed, contiguous
  __bf16* wkt = wqt + WSZ;
  __bf16* wvt = wkt + WSZ;
  __bf16* wot = wvt + WSZ;
  __bf16* qb = wot + WSZ;                 // [B*NH][T][D]
  __bf16* kb = qb + XSZ;                  // [B*NH][T][D]
  __bf16* vtb = kb + XSZ;                 // [B*NH][D][T]
  float* biasf = (float*)(vtb + XSZ);     // 4 x 2048 f32
  __bf16* ctx = srcbf;                    // reuse (src consumed by then)

  detect_dtype<<<1, 64, 0, stream>>>((const unsigned*)src, flag, cnt);
  cvt_src<<<4096, 256, 0, stream>>>(src, srcbf, flag, (int)(XSZ / 8));
  cvt_wt<<<dim3(32, 32, 4), 256, 0, stream>>>(Wq, Wk, Wv, Wo, wqt, flag);
  cvt_bias<<<32, 256, 0, stream>>>(bq, bk, bv, bo, biasf, flag);
  // fused QKV: M=4096, N=6144, 256^2 tiles -> 16x24 = 384 blocks
  gemm8p<0><<<384, 512, 0, stream>>>(srcbf, wqt, biasf, qb, kb, vtb,
                                     nullptr, nullptr);
  attn<<<512, 256, 0, stream>>>(qb, kb, vtb, ctx, cnt);
  // out-proj: M=4096, N=2048, 256x128 tiles -> 16x16 = 256 blocks (1 round)
  gemm8p<1><<<256, 512, 0, stream>>>(ctx, wot, biasf + 6144, nullptr,
                                     nullptr, nullptr, flag, d_out);
}

// Round 7
// 415.120 us; speedup vs baseline: 1.0664x; 1.0664x over previous
//
#include <hip/hip_runtime.h>
#include <hip/hip_bf16.h>

typedef float f32x4 __attribute__((ext_vector_type(4)));
typedef __bf16 bf16x8v __attribute__((ext_vector_type(8)));
typedef __bf16 bf16x4v __attribute__((ext_vector_type(4)));
typedef unsigned uint2v __attribute__((ext_vector_type(2)));
typedef bf16x8v __attribute__((may_alias)) bf16x8;
typedef bf16x4v __attribute__((may_alias)) bf16x4;
typedef uint2v __attribute__((may_alias)) u32x2;

typedef __attribute__((address_space(1))) const void gvoid_t;
typedef __attribute__((address_space(3))) void lvoid_t;

#define DEVINL __device__ __forceinline__

#define BDIM 2
#define TDIM 2048
#define CDIM 2048
#define NHEAD 16
#define DHEAD 128
#define MROWS 4096
#define WSZ ((size_t)CDIM * CDIM)
#define XSZ ((size_t)MROWS * CDIM)

// barrier without the compiler's conservative vmcnt(0) drain: LDS ops are
// flushed (lgkmcnt), in-flight global prefetch loads stay in flight.
#define BARRIER_LGKM() asm volatile("s_waitcnt lgkmcnt(0)\ns_barrier" ::: "memory")

DEVINL __bf16 f2bf(float f) {
  unsigned u = __builtin_bit_cast(unsigned, f);
  u += 0x7fffu + ((u >> 16) & 1u);  // RNE
  unsigned short h = (unsigned short)(u >> 16);
  return __builtin_bit_cast(__bf16, h);
}

// pack two f32 -> two bf16 (truncation) in one v_perm
DEVINL unsigned pk2bf_trunc(float lo, float hi) {
  return __builtin_amdgcn_perm(__builtin_bit_cast(unsigned, hi),
                               __builtin_bit_cast(unsigned, lo), 0x07060302);
}

DEVINL void gl2lds16(const void* g, void* l) {
  __builtin_amdgcn_global_load_lds((gvoid_t*)g, (lvoid_t*)l, 16, 0, 0);
}

// Per-wave dtype self-detect (replaces the detect_dtype kernel + flag
// round-trip): every wave loads the SAME 256 B of src (L2/L3 broadcast-hot)
// and votes on bf16-plausible exponents. All waves compute the identical
// value, so no cross-wave communication is needed.
DEVINL int wave_detect(const unsigned* __restrict__ w) {
  const int l = threadIdx.x & 63;
  const unsigned word = w[l];
  const unsigned e = (word >> 7) & 0xFFu;
  const int vote = (e >= 0x70u && e <= 0x87u) ? 1 : 0;
  const unsigned long long m = __ballot(vote);
  return (__popcll(m) >= 32) ? 1 : 0;
}

// ---------------------------------------------------------------------------
// src conversion + (blocks >= 4096) bias conversion, fused to cut a launch.
__global__ __launch_bounds__(256) void cvt_src(
    const void* __restrict__ in, __bf16* __restrict__ out, int n8,
    const void* __restrict__ b0, const void* __restrict__ b1,
    const void* __restrict__ b2, const void* __restrict__ b3,
    float* __restrict__ biasf) {
  const int fl = wave_detect((const unsigned*)in);
  const int bi = blockIdx.x;
  if (bi >= 4096) {  // bias tail: 32 blocks x 256 = 8192 entries
    const int i = (bi - 4096) * 256 + threadIdx.x;
    const void* b = (i < 2048) ? b0 : (i < 4096) ? b1 : (i < 6144) ? b2 : b3;
    const int idx = i & 2047;
    biasf[i] = fl ? (float)((const __bf16*)b)[idx] : ((const float*)b)[idx];
    return;
  }
  const int i = bi * 256 + threadIdx.x;
  if (i >= n8) return;
  if (fl) {
    ((bf16x8*)out)[i] = ((const bf16x8*)in)[i];
  } else {
    const float* f = (const float*)in + (size_t)i * 8;
    bf16x8v v;
#pragma unroll
    for (int j = 0; j < 8; ++j) v[j] = f2bf(f[j]);
    ((bf16x8*)out)[i] = v;
  }
}

// ---------------------------------------------------------------------------
__global__ __launch_bounds__(256) void cvt_wt(
    const void* __restrict__ w0, const void* __restrict__ w1,
    const void* __restrict__ w2, const void* __restrict__ w3,
    __bf16* __restrict__ out, const unsigned* __restrict__ srcw) {
  __shared__ __attribute__((aligned(16))) __bf16 tile[64][68];
  const void* W = (blockIdx.z == 0) ? w0 : (blockIdx.z == 1) ? w1
                : (blockIdx.z == 2) ? w2 : w3;
  __bf16* Wt = out + (size_t)blockIdx.z * WSZ;
  const int tx = threadIdx.x & 63, ty = threadIdx.x >> 6;
  const int k0 = blockIdx.x * 64, n0 = blockIdx.y * 64;
  const int fl = wave_detect(srcw);
#pragma unroll
  for (int i = ty; i < 64; i += 4) {
    const size_t off = (size_t)(k0 + i) * CDIM + n0 + tx;
    const float v = fl ? (float)((const __bf16*)W)[off] : ((const float*)W)[off];
    tile[i][tx] = f2bf(v);
  }
  __syncthreads();
#pragma unroll
  for (int i = ty; i < 64; i += 4)
    Wt[(size_t)(n0 + i) * CDIM + k0 + tx] = tile[tx][i];
}

// ---------------------------------------------------------------------------
// Counted-vmcnt half-K ring GEMM — R5 variant, the best-measured GEMM of the
// session (136.0 us QKV, MfmaUtil 32.4). FROZEN: six schedule structures
// (R0,R2,R3,R4,R5,R6) all land at MfmaUtil 27-33% with MFMA-busy time pinned
// at the 41-44 us peak-rate floor — the ~70% idle is a 1-2 block/CU
// barrier/latency structural invariant this session could not break (m201's
// +38-73% lever did not reproduce; R6's faithful assembly was WORSE).
// Details: BM=128, BN=256, BK=64 as two K=32 halves in a 4-slot ring
// (96 KiB); 8 waves of 64x64; per-phase {ds_read | gl2lds | lgkm-bar | MFMA};
// steady-state vmcnt(6), never 0 until the tail. Pair-line LDS layout with
// XOR involution, pre-swizzled global source -> measured-zero bank conflicts.
template <int MODE>
__global__ __launch_bounds__(512, 2) void gemmring(
    const __bf16* __restrict__ A, const __bf16* __restrict__ Bt,
    const float* __restrict__ bias, __bf16* __restrict__ qb,
    __bf16* __restrict__ kb, __bf16* __restrict__ vtb,
    const unsigned* __restrict__ srcw, void* __restrict__ outp) {
  constexpr int K = CDIM;
  constexpr int NKT = K / 64;  // 32 K-tiles, 64 halves
  __shared__ __attribute__((aligned(16))) __bf16 Asl[4][128 * 32];
  __shared__ __attribute__((aligned(16))) __bf16 Bsl[4][256 * 32];

  const int tid = threadIdx.x;
  const int w = tid >> 6, l = tid & 63;
  const int quad = l >> 4, l16 = l & 15;
  const int wm = w >> 2, wn = w & 3;  // wave tile 64x64

  const int bid = blockIdx.x;
  const int bm = bid & 31, bn = bid >> 5;  // bm-fastest: B panel L2-shared
  const int m0 = bm * 128, n0 = bn * 256;

  // staging source pre-swizzle (inverse of the pair-line layout)
  const int ls = (tid & 7) ^ ((tid >> 3) & 7);
  const int rbase = 2 * (tid >> 3) + (ls >> 2);  // 0..127
  const int cb8 = (ls & 3) * 8;
  const __bf16* gAh = A + (size_t)(m0 + rbase) * K + cb8;
  const __bf16* gBh = Bt + (size_t)(n0 + rbase) * K + cb8;

  // fragment read addressing (per-lane constant)
  const int L2 = l16 >> 1;
  const int physr = (((l16 & 1) << 2) + quad) ^ L2;
  const int lane_e = L2 * 64 + physr * 8;  // element offset within slot

#define STAGE_A(h)                                                       \
  gl2lds16(gAh + (size_t)(((h) >> 1) * 64 + ((h) & 1) * 32),             \
           (__bf16*)Asl[(h) & 3] + w * 512)
#define STAGE_B(h, e)                                                    \
  gl2lds16(gBh + (size_t)(e) * 128 * K +                                 \
               (((h) >> 1) * 64 + ((h) & 1) * 32),                       \
           (__bf16*)Bsl[(h) & 3] + (e) * 4096 + w * 512)

  f32x4 acc[4][4];
#pragma unroll
  for (int i = 0; i < 4; ++i)
#pragma unroll
    for (int j = 0; j < 4; ++j) acc[i][j] = (f32x4){0.f, 0.f, 0.f, 0.f};

  // prologue: halves 0,1,2 (9 loads); certify h0 with vmcnt(6)+barrier.
  STAGE_A(0); STAGE_B(0, 0); STAGE_B(0, 1);
  STAGE_A(1); STAGE_B(1, 0); STAGE_B(1, 1);
  STAGE_A(2); STAGE_B(2, 0); STAGE_B(2, 1);
  asm volatile("s_waitcnt vmcnt(6)" ::: "memory");
  __builtin_amdgcn_sched_barrier(0);
  __builtin_amdgcn_s_barrier();

#define MFMA8(NF0)                                                        \
  __builtin_amdgcn_s_setprio(1);                                          \
  _Pragma("unroll") for (int mi = 0; mi < 4; ++mi) {                      \
    acc[mi][(NF0)] = __builtin_amdgcn_mfma_f32_16x16x32_bf16(             \
        afr[mi], bfr[0], acc[mi][(NF0)], 0, 0, 0);                        \
    acc[mi][(NF0) + 1] = __builtin_amdgcn_mfma_f32_16x16x32_bf16(         \
        afr[mi], bfr[1], acc[mi][(NF0) + 1], 0, 0, 0);                    \
  }                                                                       \
  __builtin_amdgcn_s_setprio(0);

#define LGKM_BAR()                                                        \
  __builtin_amdgcn_s_barrier();                                           \
  asm volatile("s_waitcnt lgkmcnt(0)" ::: "memory");                      \
  __builtin_amdgcn_sched_barrier(0)

  for (int kt = 0; kt < NKT; ++kt) {
    const int h0 = 2 * kt;           // this tile's halves: h0, h0+1
    const __bf16* Ab0 = Asl[h0 & 3];
    const __bf16* Bb0 = Bsl[h0 & 3];
    const __bf16* Ab1 = Asl[(h0 + 1) & 3];
    const __bf16* Bb1 = Bsl[(h0 + 1) & 3];
    bf16x8 afr[4], bfr[2];

    // ---- P1: ks0, nf0-1; stage A(h0+3), B(h0+3,e0)
#pragma unroll
    for (int mi = 0; mi < 4; ++mi)
      afr[mi] = *(const bf16x8*)&Ab0[(wm * 64 + mi * 16) * 32 + lane_e];
    bfr[0] = *(const bf16x8*)&Bb0[(wn * 64 + 0 * 16) * 32 + lane_e];
    bfr[1] = *(const bf16x8*)&Bb0[(wn * 64 + 1 * 16) * 32 + lane_e];
    if (kt <= NKT - 2) { STAGE_A(h0 + 3); STAGE_B(h0 + 3, 0); }
    LGKM_BAR();
    MFMA8(0)
    __builtin_amdgcn_s_barrier();

    // ---- P2: ks0, nf2-3; stage B(h0+3,e1); end-wait certifies h0+1
    bfr[0] = *(const bf16x8*)&Bb0[(wn * 64 + 2 * 16) * 32 + lane_e];
    bfr[1] = *(const bf16x8*)&Bb0[(wn * 64 + 3 * 16) * 32 + lane_e];
    if (kt <= NKT - 2) { STAGE_B(h0 + 3, 1); }
    LGKM_BAR();
    MFMA8(2)
    if (kt < NKT - 1)
      asm volatile("s_waitcnt vmcnt(6)" ::: "memory");
    else
      asm volatile("s_waitcnt vmcnt(0)" ::: "memory");
    __builtin_amdgcn_sched_barrier(0);
    __builtin_amdgcn_s_barrier();

    // ---- P3: ks1, nf0-1; stage A(h0+4), B(h0+4,e0) into freed h0 slots
#pragma unroll
    for (int mi = 0; mi < 4; ++mi)
      afr[mi] = *(const bf16x8*)&Ab1[(wm * 64 + mi * 16) * 32 + lane_e];
    bfr[0] = *(const bf16x8*)&Bb1[(wn * 64 + 0 * 16) * 32 + lane_e];
    bfr[1] = *(const bf16x8*)&Bb1[(wn * 64 + 1 * 16) * 32 + lane_e];
    if (kt <= NKT - 3) { STAGE_A(h0 + 4); STAGE_B(h0 + 4, 0); }
    LGKM_BAR();
    MFMA8(0)
    __builtin_amdgcn_s_barrier();

    // ---- P4: ks1, nf2-3; stage B(h0+4,e1); end-wait certifies h0+2
    bfr[0] = *(const bf16x8*)&Bb1[(wn * 64 + 2 * 16) * 32 + lane_e];
    bfr[1] = *(const bf16x8*)&Bb1[(wn * 64 + 3 * 16) * 32 + lane_e];
    if (kt <= NKT - 3) { STAGE_B(h0 + 4, 1); }
    LGKM_BAR();
    MFMA8(2)
    if (kt < NKT - 2)
      asm volatile("s_waitcnt vmcnt(6)" ::: "memory");
    else if (kt == NKT - 2)
      asm volatile("s_waitcnt vmcnt(3)" ::: "memory");
    __builtin_amdgcn_sched_barrier(0);
    __builtin_amdgcn_s_barrier();
  }
#undef MFMA8
#undef LGKM_BAR
#undef STAGE_A
#undef STAGE_B

  if (MODE == 0) {
    // QKV scatter: Q,K -> [b,h,t,d]; V -> [b,h,d,t] (bf16x4). BN=256
    // divides 2048 -> mat uniform per block.
    const int mat = n0 >> 11;  // 0=Q 1=K 2=V
#pragma unroll
    for (int nf = 0; nf < 4; ++nf) {
      const int n = n0 + wn * 64 + nf * 16 + l16;  // 0..6143
      const int nn = n & 2047;
      const int h = nn >> 7, d = nn & 127;
      const float bv = bias[n];
#pragma unroll
      for (int mi = 0; mi < 4; ++mi) {
        const int mbase = m0 + wm * 64 + mi * 16 + quad * 4;
        const int bb = mbase >> 11, t = mbase & 2047;
        if (mat == 2) {
          bf16x4v v4;
#pragma unroll
          for (int r = 0; r < 4; ++r) v4[r] = f2bf(acc[mi][nf][r] + bv);
          *(bf16x4*)&vtb[((size_t)(bb * NHEAD + h) * DHEAD + d) * TDIM + t] = v4;
        } else {
          __bf16* op = (mat == 0) ? qb : kb;
#pragma unroll
          for (int r = 0; r < 4; ++r)
            op[((size_t)(bb * NHEAD + h) * TDIM + t + r) * DHEAD + d] =
                f2bf(acc[mi][nf][r] + bv);
        }
      }
    }
  } else {
    const int ofl = wave_detect(srcw);
#pragma unroll
    for (int nf = 0; nf < 4; ++nf) {
      const int n = n0 + wn * 64 + nf * 16 + l16;
      const float bv = bias[n];
#pragma unroll
      for (int mi = 0; mi < 4; ++mi) {
#pragma unroll
        for (int r = 0; r < 4; ++r) {
          const int m = m0 + wm * 64 + mi * 16 + quad * 4 + r;
          const float v = acc[mi][nf][r] + bv;
          if (ofl) ((__bf16*)outp)[(size_t)m * CDIM + n] = f2bf(v);
          else     ((float*)outp)[(size_t)m * CDIM + n] = v;
        }
      }
    }
  }
}

// ---------------------------------------------------------------------------
// Flash-style causal attention. This round: +T5 setprio around both MFMA
// clusters (m191: +4-7% attn) and +T13 defer-max with THR=8 exp2-units
// (m214 v23: +5%): keep the old running max while per-tile growth <= 8, so
// P <= 2^8 (bf16/f32 headroom fine) and the O(64)-mul rescale ~never fires
// after the first s-block.
__global__ __launch_bounds__(256, 2) void attn(
    const __bf16* __restrict__ Q, const __bf16* __restrict__ K,
    const __bf16* __restrict__ Vt, __bf16* __restrict__ ctx,
    int* __restrict__ cnt) {
  constexpr float CSC = 0.12753139726f;  // log2(e)/sqrt(128)
  __shared__ __attribute__((aligned(16))) __bf16 Kls[64 * 128];   // [s][d]
  __shared__ __attribute__((aligned(16))) __bf16 Vls[128 * 64];   // [d][s]
  __shared__ __attribute__((aligned(16))) __bf16 Pls[4][32 * 64]; // [t][s]
  __shared__ int jobLds;

  const int tid = threadIdx.x;
  const int w = tid >> 6, l = tid & 63, quad = l >> 4, l16 = l & 15;

  const int krow = tid >> 4;                 // 0..15, +16 per pass
  const int kcol = tid & 15;
  const int kldsoff = ((kcol ^ krow) * 8);
  const int vrow = tid >> 3;                 // 0..31, +32 per pass
  const int vcol = tid & 7;
  const int vldsoff = ((vcol ^ (vrow & 7)) * 8);

  for (;;) {
    __syncthreads();
    if (tid == 0) jobLds = atomicAdd(cnt, 1);
    __syncthreads();
    const int j = jobLds;
    if (j >= 512) break;
    const int qt = 15 - (j >> 5);   // all qt=15 jobs first (LPT)
    const int bh = j & 31;
    const int t0w = qt * 128 + w * 32;
    const __bf16* Qbh = Q + (size_t)bh * TDIM * DHEAD;
    const __bf16* Kbh = K + (size_t)bh * TDIM * DHEAD;
    const __bf16* Vbh = Vt + (size_t)bh * TDIM * DHEAD;

    bf16x8 qf[2][4];
#pragma unroll
    for (int tt = 0; tt < 2; ++tt)
#pragma unroll
      for (int ks = 0; ks < 4; ++ks)
        qf[tt][ks] = *(const bf16x8*)(Qbh +
                     (size_t)(t0w + tt * 16 + l16) * DHEAD + ks * 32 + quad * 8);

    f32x4 oacc[8][2];
#pragma unroll
    for (int dt = 0; dt < 8; ++dt)
#pragma unroll
      for (int tt = 0; tt < 2; ++tt) oacc[dt][tt] = (f32x4){0.f, 0.f, 0.f, 0.f};
    float mrow[2] = {-1e30f, -1e30f};
    float lrow[2] = {0.f, 0.f};

    const int nsb = 2 * (qt + 1);

    // prefetch s-block 0 into regs
    bf16x8 kr[4], vr[4];
#pragma unroll
    for (int p = 0; p < 4; ++p)
      kr[p] = *(const bf16x8*)(Kbh + (size_t)(p * 16 + krow) * DHEAD + kcol * 8);
#pragma unroll
    for (int p = 0; p < 4; ++p)
      vr[p] = *(const bf16x8*)(Vbh + (size_t)(p * 32 + vrow) * TDIM + vcol * 8);

    for (int sb = 0; sb < nsb; ++sb) {
      const int s0 = sb * 64;
      BARRIER_LGKM();  // prior iteration's LDS reads complete
#pragma unroll
      for (int p = 0; p < 4; ++p)
        *(bf16x8*)&Kls[(p * 16 + krow) * 128 + kldsoff] = kr[p];
#pragma unroll
      for (int p = 0; p < 4; ++p)
        *(bf16x8*)&Vls[(p * 32 + vrow) * 64 + vldsoff] = vr[p];
      if (sb + 1 < nsb) {
        const int s1 = s0 + 64;
#pragma unroll
        for (int p = 0; p < 4; ++p)
          kr[p] = *(const bf16x8*)(Kbh + (size_t)(s1 + p * 16 + krow) * DHEAD +
                                   kcol * 8);
#pragma unroll
        for (int p = 0; p < 4; ++p)
          vr[p] = *(const bf16x8*)(Vbh + (size_t)(p * 32 + vrow) * TDIM + s1 +
                                   vcol * 8);
      }
      BARRIER_LGKM();  // staging visible; prefetch loads remain in flight
      if (s0 > t0w + 31) continue;  // fully masked for this wave

      // S^T = K.Q^T : D[row=s: quad*4+r][col=t: l16]
      f32x4 sacc[4][2];
#pragma unroll
      for (int st = 0; st < 4; ++st)
#pragma unroll
        for (int tt = 0; tt < 2; ++tt) sacc[st][tt] = (f32x4){0.f, 0.f, 0.f, 0.f};
      __builtin_amdgcn_s_setprio(1);
#pragma unroll
      for (int ks = 0; ks < 4; ++ks) {
        bf16x8 kf[4];
#pragma unroll
        for (int st = 0; st < 4; ++st)
          kf[st] = *(const bf16x8*)&Kls[(st * 16 + l16) * 128 +
                                        (((ks * 4 + quad) ^ l16) * 8)];
#pragma unroll
        for (int st = 0; st < 4; ++st)
#pragma unroll
          for (int tt = 0; tt < 2; ++tt)
            sacc[st][tt] = __builtin_amdgcn_mfma_f32_16x16x32_bf16(
                kf[st], qf[tt][ks], sacc[st][tt], 0, 0, 0);
      }
      __builtin_amdgcn_s_setprio(0);
      if (s0 + 63 > t0w) {  // causal mask near diagonal
#pragma unroll
        for (int st = 0; st < 4; ++st)
#pragma unroll
          for (int tt = 0; tt < 2; ++tt)
#pragma unroll
            for (int r = 0; r < 4; ++r) {
              const int s = s0 + st * 16 + quad * 4 + r;
              const int t = t0w + tt * 16 + l16;
              if (s > t) sacc[st][tt][r] = -1e30f;
            }
      }
      // online softmax per t-column (defer-max: rescale only when growth
      // exceeds 8 exp2-units; P stays bounded by 2^8)
#pragma unroll
      for (int tt = 0; tt < 2; ++tt) {
        float vm = -1e30f;
#pragma unroll
        for (int st = 0; st < 4; ++st)
#pragma unroll
          for (int r = 0; r < 4; ++r) vm = fmaxf(vm, sacc[st][tt][r]);
        vm = fmaxf(vm, __shfl_xor(vm, 16));
        vm = fmaxf(vm, __shfl_xor(vm, 32));
        if (__ballot((vm - mrow[tt]) * CSC > 8.0f)) {
          const float mn = fmaxf(mrow[tt], vm);
          const float alpha = exp2f((mrow[tt] - mn) * CSC);
          lrow[tt] *= alpha;
#pragma unroll
          for (int dt = 0; dt < 8; ++dt)
#pragma unroll
            for (int r = 0; r < 4; ++r) oacc[dt][tt][r] *= alpha;
          mrow[tt] = mn;
        }
        const float mcur = mrow[tt];
        float rs = 0.f;
#pragma unroll
        for (int st = 0; st < 4; ++st) {
          const float p0 = exp2f((sacc[st][tt][0] - mcur) * CSC);
          const float p1 = exp2f((sacc[st][tt][1] - mcur) * CSC);
          const float p2 = exp2f((sacc[st][tt][2] - mcur) * CSC);
          const float p3 = exp2f((sacc[st][tt][3] - mcur) * CSC);
          rs += (p0 + p1) + (p2 + p3);
          u32x2 pk = {pk2bf_trunc(p0, p1), pk2bf_trunc(p2, p3)};
          *(u32x2*)&Pls[w][(tt * 16 + l16) * 64 +
                           (((st * 2 + (quad >> 1)) ^ (l16 & 7)) * 8) +
                           (quad & 1) * 4] = pk;
        }
        rs += __shfl_xor(rs, 16);
        rs += __shfl_xor(rs, 32);
        lrow[tt] += rs;
      }
      // intra-wave P write->read ordering (wave-private region, no barrier)
      asm volatile("s_waitcnt lgkmcnt(0)" ::: "memory");
      // O^T += V^T.P^T : D[row=d][col=t]
      __builtin_amdgcn_s_setprio(1);
#pragma unroll
      for (int ks = 0; ks < 2; ++ks) {
        bf16x8 pf[2];
#pragma unroll
        for (int tt = 0; tt < 2; ++tt)
          pf[tt] = *(const bf16x8*)&Pls[w][(tt * 16 + l16) * 64 +
                                           (((ks * 4 + quad) ^ (l16 & 7)) * 8)];
#pragma unroll
        for (int dt = 0; dt < 8; ++dt) {
          const bf16x8 vf =
              *(const bf16x8*)&Vls[(dt * 16 + l16) * 64 +
                                   (((ks * 4 + quad) ^ (l16 & 7)) * 8)];
#pragma unroll
          for (int tt = 0; tt < 2; ++tt)
            oacc[dt][tt] = __builtin_amdgcn_mfma_f32_16x16x32_bf16(
                vf, pf[tt], oacc[dt][tt], 0, 0, 0);
        }
      }
      __builtin_amdgcn_s_setprio(0);
    }

    // epilogue: O^T[d][t]/l -> ctx[b][t][h*128+d], bf16x4 stores
    const int b = bh >> 4, h = bh & 15;
#pragma unroll
    for (int tt = 0; tt < 2; ++tt) {
      const float rinv = 1.0f / lrow[tt];
      const int t = t0w + tt * 16 + l16;
      __bf16* cp = ctx + ((size_t)(b * TDIM + t)) * CDIM + h * DHEAD;
#pragma unroll
      for (int dt = 0; dt < 8; ++dt) {
        bf16x4v v4;
#pragma unroll
        for (int r = 0; r < 4; ++r) v4[r] = f2bf(oacc[dt][tt][r] * rinv);
        *(bf16x4*)&cp[dt * 16 + quad * 4] = v4;
      }
    }
  }
}

// ---------------------------------------------------------------------------
extern "C" void kernel_launch(void* const* d_in, const int* in_sizes, int n_in,
                              void* d_out, int out_size, void* d_ws,
                              size_t ws_size, hipStream_t stream) {
  const void* src = d_in[0];
  const void* Wq = d_in[1];
  const void* bq = d_in[2];
  const void* Wk = d_in[3];
  const void* bk = d_in[4];
  const void* Wv = d_in[5];
  const void* bv = d_in[6];
  const void* Wo = d_in[7];
  const void* bo = d_in[8];

  char* wsb = (char*)d_ws;
  int* cnt = (int*)(wsb + 128);           // +128 (work-steal counter)
  __bf16* srcbf = (__bf16*)(wsb + 256);
  __bf16* wqt = srcbf + XSZ;              // q,k,v,o transposed, contiguous
  __bf16* wkt = wqt + WSZ;
  __bf16* wvt = wkt + WSZ;
  __bf16* wot = wvt + WSZ;
  __bf16* qb = wot + WSZ;                 // [B*NH][T][D]
  __bf16* kb = qb + XSZ;                  // [B*NH][T][D]
  __bf16* vtb = kb + XSZ;                 // [B*NH][D][T]
  float* biasf = (float*)(vtb + XSZ);     // 4 x 2048 f32
  __bf16* ctx = srcbf;                    // reuse (src consumed by then)
  (void)wkt; (void)wvt;

  hipMemsetAsync(cnt, 0, sizeof(int), stream);
  // src conversion + bias conversion fused (4096 + 32 blocks)
  cvt_src<<<4128, 256, 0, stream>>>(src, srcbf, (int)(XSZ / 8), bq, bk, bv,
                                    bo, biasf);
  cvt_wt<<<dim3(32, 32, 4), 256, 0, stream>>>(Wq, Wk, Wv, Wo, wqt,
                                              (const unsigned*)src);
  // fused QKV: M=4096, N=6144, BM=128 x BN=256 -> 32x24 = 768 blocks
  // (3.0 exact CU rounds at 1 block/CU)
  gemmring<0><<<768, 512, 0, stream>>>(srcbf, wqt, biasf, qb, kb, vtb,
                                       nullptr, nullptr);
  attn<<<512, 256, 0, stream>>>(qb, kb, vtb, ctx, cnt);
  // out-proj: M=4096, N=2048 -> 32x8 = 256 blocks (1.0 round)
  gemmring<1><<<256, 512, 0, stream>>>(ctx, wot, biasf + 6144, nullptr,
                                       nullptr, nullptr, (const unsigned*)src,
                                       d_out);
}

// Round 8
// 397.006 us; speedup vs baseline: 1.1151x; 1.0456x over previous
//
#include <hip/hip_runtime.h>
#include <hip/hip_bf16.h>

typedef float f32x4 __attribute__((ext_vector_type(4)));
typedef __bf16 bf16x8v __attribute__((ext_vector_type(8)));
typedef __bf16 bf16x4v __attribute__((ext_vector_type(4)));
typedef unsigned uint2v __attribute__((ext_vector_type(2)));
typedef bf16x8v __attribute__((may_alias)) bf16x8;
typedef bf16x4v __attribute__((may_alias)) bf16x4;
typedef uint2v __attribute__((may_alias)) u32x2;

typedef __attribute__((address_space(1))) const void gvoid_t;
typedef __attribute__((address_space(3))) void lvoid_t;

#define DEVINL __device__ __forceinline__

#define BDIM 2
#define TDIM 2048
#define CDIM 2048
#define NHEAD 16
#define DHEAD 128
#define MROWS 4096
#define WSZ ((size_t)CDIM * CDIM)
#define XSZ ((size_t)MROWS * CDIM)

// barrier without the compiler's conservative vmcnt(0) drain: LDS ops are
// flushed (lgkmcnt), in-flight global prefetch loads stay in flight.
#define BARRIER_LGKM() asm volatile("s_waitcnt lgkmcnt(0)\ns_barrier" ::: "memory")

DEVINL __bf16 f2bf(float f) {
  unsigned u = __builtin_bit_cast(unsigned, f);
  u += 0x7fffu + ((u >> 16) & 1u);  // RNE
  unsigned short h = (unsigned short)(u >> 16);
  return __builtin_bit_cast(__bf16, h);
}

// pack two f32 -> two bf16 (truncation) in one v_perm
DEVINL unsigned pk2bf_trunc(float lo, float hi) {
  return __builtin_amdgcn_perm(__builtin_bit_cast(unsigned, hi),
                               __builtin_bit_cast(unsigned, lo), 0x07060302);
}

DEVINL void gl2lds16(const void* g, void* l) {
  __builtin_amdgcn_global_load_lds((gvoid_t*)g, (lvoid_t*)l, 16, 0, 0);
}

// Per-wave dtype self-detect: every wave loads the SAME 256 B of src
// (L2/L3 broadcast-hot) and votes on bf16-plausible exponents.
DEVINL int wave_detect(const unsigned* __restrict__ w) {
  const int l = threadIdx.x & 63;
  const unsigned word = w[l];
  const unsigned e = (word >> 7) & 0xFFu;
  const int vote = (e >= 0x70u && e <= 0x87u) ? 1 : 0;
  const unsigned long long m = __ballot(vote);
  return (__popcll(m) >= 32) ? 1 : 0;
}

// ---------------------------------------------------------------------------
// Fused prologue (one launch instead of memset+cvt_src+cvt_bias+cvt_wt):
//   blocks [0,4096):      src -> bf16
//   blocks [4096,4128):   biases -> f32 (+ block 4096 zeroes the attn counter)
//   blocks [4128,8224):   4 weights -> bf16 transposed (64x64 LDS tiles)
__global__ __launch_bounds__(256) void prologue(
    const void* __restrict__ src, __bf16* __restrict__ srcbf, int n8,
    const void* __restrict__ b0, const void* __restrict__ b1,
    const void* __restrict__ b2, const void* __restrict__ b3,
    float* __restrict__ biasf, const void* __restrict__ w0,
    const void* __restrict__ w1, const void* __restrict__ w2,
    const void* __restrict__ w3, __bf16* __restrict__ wt,
    int* __restrict__ cnt) {
  __shared__ __attribute__((aligned(16))) __bf16 tile[64][68];
  const int fl = wave_detect((const unsigned*)src);
  const int bi = blockIdx.x;
  if (bi < 4096) {  // src conversion
    const int i = bi * 256 + threadIdx.x;
    if (i >= n8) return;
    if (fl) {
      ((bf16x8*)srcbf)[i] = ((const bf16x8*)src)[i];
    } else {
      const float* f = (const float*)src + (size_t)i * 8;
      bf16x8v v;
#pragma unroll
      for (int j = 0; j < 8; ++j) v[j] = f2bf(f[j]);
      ((bf16x8*)srcbf)[i] = v;
    }
    return;
  }
  if (bi < 4128) {  // bias conversion + counter zero
    if (bi == 4096 && threadIdx.x == 0) *cnt = 0;
    const int i = (bi - 4096) * 256 + threadIdx.x;  // 0..8191
    const void* b = (i < 2048) ? b0 : (i < 4096) ? b1 : (i < 6144) ? b2 : b3;
    const int idx = i & 2047;
    biasf[i] = fl ? (float)((const __bf16*)b)[idx] : ((const float*)b)[idx];
    return;
  }
  // weight transpose: idx -> (z weight, by n-tile, bx k-tile)
  const int idx = bi - 4128;
  const int z = idx >> 10, rem = idx & 1023;
  const int by = rem >> 5, bx = rem & 31;
  const void* W = (z == 0) ? w0 : (z == 1) ? w1 : (z == 2) ? w2 : w3;
  __bf16* Wt = wt + (size_t)z * WSZ;
  const int tx = threadIdx.x & 63, ty = threadIdx.x >> 6;
  const int k0 = bx * 64, n0 = by * 64;
#pragma unroll
  for (int i = ty; i < 64; i += 4) {
    const size_t off = (size_t)(k0 + i) * CDIM + n0 + tx;
    const float v = fl ? (float)((const __bf16*)W)[off] : ((const float*)W)[off];
    tile[i][tx] = f2bf(v);
  }
  __syncthreads();
#pragma unroll
  for (int i = ty; i < 64; i += 4)
    Wt[(size_t)(n0 + i) * CDIM + k0 + tx] = tile[tx][i];
}

// ---------------------------------------------------------------------------
// Counted-vmcnt half-K RING-3 GEMM. R8 change vs the R5/R7 ring-4: 3 slots
// per operand (A 3x8KB + B 3x16KB = 72 KiB) -> 2 blocks/CU. Rationale: all
// R2-R6 structures ran at 1 block/CU (96-131 KiB LDS) and were pinned at
// MfmaUtil 27-33% with MFMA-busy = the 41-44 us peak-rate floor — the idle
// is barrier time with no co-resident block to hide it. m97's 874-TF
// reference runs 3 blocks/CU; m114 shows cross-block MFMA/VALU overlap is
// what fills the drain windows. Ring-3 keeps the counted-vmcnt discipline:
//   slots rotate roles (r0,r1,r2)<-(r2,r0,r1) per K-tile; tile kt reads
//   halves h0=2kt (r0), h0+1 (r1); stages h0+2 into r2 (never read this
//   tile) and h0+3 into r0 (write issued after the P2-close barrier that
//   postdates r0's last read).
// Per-wave ledger (3 loads/half: 1 A + 2 B; 6/tile):
//   prologue: h0,h1 (6 loads); vmcnt(3) certifies h0.
//   end-P2 vmcnt(3): outstanding = prevP3P4(3)+P1P2(3) -> certifies h0+1.
//   end-P4 vmcnt(3): outstanding = P1..P4 (6) -> certifies h0+2.
//   vmcnt(0) only at last tile's P2. Flight time 2-4 phases >= HBM latency.
// LDS pair-line layout + XOR involution and all addressing identical to the
// R5-R7 functionally-verified kernel; measured-zero bank conflicts.
template <int MODE>
__global__ __launch_bounds__(512, 4) void gemmring(
    const __bf16* __restrict__ A, const __bf16* __restrict__ Bt,
    const float* __restrict__ bias, __bf16* __restrict__ qb,
    __bf16* __restrict__ kb, __bf16* __restrict__ vtb,
    const unsigned* __restrict__ srcw, void* __restrict__ outp) {
  constexpr int K = CDIM;
  constexpr int NKT = K / 64;  // 32 K-tiles, 64 halves
  __shared__ __attribute__((aligned(16))) __bf16 Asl[3][128 * 32];
  __shared__ __attribute__((aligned(16))) __bf16 Bsl[3][256 * 32];

  const int tid = threadIdx.x;
  const int w = tid >> 6, l = tid & 63;
  const int quad = l >> 4, l16 = l & 15;
  const int wm = w >> 2, wn = w & 3;  // wave tile 64x64

  const int bid = blockIdx.x;
  const int bm = bid & 31, bn = bid >> 5;  // bm-fastest: B panel L2-shared
  const int m0 = bm * 128, n0 = bn * 256;

  // staging source pre-swizzle (inverse of the pair-line layout)
  const int ls = (tid & 7) ^ ((tid >> 3) & 7);
  const int rbase = 2 * (tid >> 3) + (ls >> 2);  // 0..127
  const int cb8 = (ls & 3) * 8;
  const __bf16* gAh = A + (size_t)(m0 + rbase) * K + cb8;
  const __bf16* gBh = Bt + (size_t)(n0 + rbase) * K + cb8;

  // fragment read addressing (per-lane constant)
  const int L2 = l16 >> 1;
  const int physr = (((l16 & 1) << 2) + quad) ^ L2;
  const int lane_e = L2 * 64 + physr * 8;  // element offset within slot

  // slot role pointers: a0/b0 = half h0, a1/b1 = h0+1, a2/b2 = h0+2 dest
  __bf16 *a0 = (__bf16*)Asl[0], *a1 = (__bf16*)Asl[1], *a2 = (__bf16*)Asl[2];
  __bf16 *b0 = (__bf16*)Bsl[0], *b1 = (__bf16*)Bsl[1], *b2 = (__bf16*)Bsl[2];

#define STAGE_A(dst, h)                                                   \
  gl2lds16(gAh + (size_t)(((h) >> 1) * 64 + ((h) & 1) * 32), (dst) + w * 512)
#define STAGE_B(dst, h, e)                                                \
  gl2lds16(gBh + (size_t)(e) * 128 * K +                                  \
               (((h) >> 1) * 64 + ((h) & 1) * 32),                        \
           (dst) + (e) * 4096 + w * 512)

  f32x4 acc[4][4];
#pragma unroll
  for (int i = 0; i < 4; ++i)
#pragma unroll
    for (int j = 0; j < 4; ++j) acc[i][j] = (f32x4){0.f, 0.f, 0.f, 0.f};

  // prologue: halves 0,1 (6 loads); vmcnt(3) certifies h0.
  STAGE_A(a0, 0); STAGE_B(b0, 0, 0); STAGE_B(b0, 0, 1);
  STAGE_A(a1, 1); STAGE_B(b1, 1, 0); STAGE_B(b1, 1, 1);
  asm volatile("s_waitcnt vmcnt(3)" ::: "memory");
  __builtin_amdgcn_sched_barrier(0);
  __builtin_amdgcn_s_barrier();

#define MFMA8(NF0)                                                        \
  __builtin_amdgcn_s_setprio(1);                                          \
  _Pragma("unroll") for (int mi = 0; mi < 4; ++mi) {                      \
    acc[mi][(NF0)] = __builtin_amdgcn_mfma_f32_16x16x32_bf16(             \
        afr[mi], bfr[0], acc[mi][(NF0)], 0, 0, 0);                        \
    acc[mi][(NF0) + 1] = __builtin_amdgcn_mfma_f32_16x16x32_bf16(         \
        afr[mi], bfr[1], acc[mi][(NF0) + 1], 0, 0, 0);                    \
  }                                                                       \
  __builtin_amdgcn_s_setprio(0);

#define LGKM_BAR()                                                        \
  __builtin_amdgcn_s_barrier();                                           \
  asm volatile("s_waitcnt lgkmcnt(0)" ::: "memory");                      \
  __builtin_amdgcn_sched_barrier(0)

  for (int kt = 0; kt < NKT; ++kt) {
    const int h0 = 2 * kt;
    const bool st = (kt < NKT - 1);
    bf16x8 afr[4], bfr[2];

    // ---- P1: h0, nf0-1; stage A(h0+2)->a2, B(h0+2,e0)->b2
#pragma unroll
    for (int mi = 0; mi < 4; ++mi)
      afr[mi] = *(const bf16x8*)&a0[(wm * 64 + mi * 16) * 32 + lane_e];
    bfr[0] = *(const bf16x8*)&b0[(wn * 64 + 0 * 16) * 32 + lane_e];
    bfr[1] = *(const bf16x8*)&b0[(wn * 64 + 1 * 16) * 32 + lane_e];
    if (st) { STAGE_A(a2, h0 + 2); STAGE_B(b2, h0 + 2, 0); }
    LGKM_BAR();
    MFMA8(0)
    __builtin_amdgcn_s_barrier();

    // ---- P2: h0, nf2-3; stage B(h0+2,e1)->b2; end-wait certifies h0+1
    bfr[0] = *(const bf16x8*)&b0[(wn * 64 + 2 * 16) * 32 + lane_e];
    bfr[1] = *(const bf16x8*)&b0[(wn * 64 + 3 * 16) * 32 + lane_e];
    if (st) { STAGE_B(b2, h0 + 2, 1); }
    LGKM_BAR();
    MFMA8(2)
    if (st)
      asm volatile("s_waitcnt vmcnt(3)" ::: "memory");
    else
      asm volatile("s_waitcnt vmcnt(0)" ::: "memory");
    __builtin_amdgcn_sched_barrier(0);
    __builtin_amdgcn_s_barrier();

    // ---- P3: h0+1, nf0-1; stage A(h0+3)->a0, B(h0+3,e0)->b0
    //      (slot r0's last read was P2; the P2-close barrier orders it)
#pragma unroll
    for (int mi = 0; mi < 4; ++mi)
      afr[mi] = *(const bf16x8*)&a1[(wm * 64 + mi * 16) * 32 + lane_e];
    bfr[0] = *(const bf16x8*)&b1[(wn * 64 + 0 * 16) * 32 + lane_e];
    bfr[1] = *(const bf16x8*)&b1[(wn * 64 + 1 * 16) * 32 + lane_e];
    if (st) { STAGE_A(a0, h0 + 3); STAGE_B(b0, h0 + 3, 0); }
    LGKM_BAR();
    MFMA8(0)
    __builtin_amdgcn_s_barrier();

    // ---- P4: h0+1, nf2-3; stage B(h0+3,e1)->b0; end-wait certifies h0+2
    bfr[0] = *(const bf16x8*)&b1[(wn * 64 + 2 * 16) * 32 + lane_e];
    bfr[1] = *(const bf16x8*)&b1[(wn * 64 + 3 * 16) * 32 + lane_e];
    if (st) { STAGE_B(b0, h0 + 3, 1); }
    LGKM_BAR();
    MFMA8(2)
    asm volatile("s_waitcnt vmcnt(3)" ::: "memory");
    __builtin_amdgcn_sched_barrier(0);
    __builtin_amdgcn_s_barrier();

    // rotate slot roles: (r0,r1,r2) <- (r2,r0,r1)
    __bf16* t;
    t = a0; a0 = a2; a2 = a1; a1 = t;
    t = b0; b0 = b2; b2 = b1; b1 = t;
  }
#undef MFMA8
#undef LGKM_BAR
#undef STAGE_A
#undef STAGE_B

  if (MODE == 0) {
    // QKV scatter: Q,K -> [b,h,t,d]; V -> [b,h,d,t] (bf16x4). BN=256
    // divides 2048 -> mat uniform per block.
    const int mat = n0 >> 11;  // 0=Q 1=K 2=V
#pragma unroll
    for (int nf = 0; nf < 4; ++nf) {
      const int n = n0 + wn * 64 + nf * 16 + l16;  // 0..6143
      const int nn = n & 2047;
      const int h = nn >> 7, d = nn & 127;
      const float bv = bias[n];
#pragma unroll
      for (int mi = 0; mi < 4; ++mi) {
        const int mbase = m0 + wm * 64 + mi * 16 + quad * 4;
        const int bb = mbase >> 11, t = mbase & 2047;
        if (mat == 2) {
          bf16x4v v4;
#pragma unroll
          for (int r = 0; r < 4; ++r) v4[r] = f2bf(acc[mi][nf][r] + bv);
          *(bf16x4*)&vtb[((size_t)(bb * NHEAD + h) * DHEAD + d) * TDIM + t] = v4;
        } else {
          __bf16* op = (mat == 0) ? qb : kb;
#pragma unroll
          for (int r = 0; r < 4; ++r)
            op[((size_t)(bb * NHEAD + h) * TDIM + t + r) * DHEAD + d] =
                f2bf(acc[mi][nf][r] + bv);
        }
      }
    }
  } else {
    const int ofl = wave_detect(srcw);
#pragma unroll
    for (int nf = 0; nf < 4; ++nf) {
      const int n = n0 + wn * 64 + nf * 16 + l16;
      const float bv = bias[n];
#pragma unroll
      for (int mi = 0; mi < 4; ++mi) {
#pragma unroll
        for (int r = 0; r < 4; ++r) {
          const int m = m0 + wm * 64 + mi * 16 + quad * 4 + r;
          const float v = acc[mi][nf][r] + bv;
          if (ofl) ((__bf16*)outp)[(size_t)m * CDIM + n] = f2bf(v);
          else     ((float*)outp)[(size_t)m * CDIM + n] = v;
        }
      }
    }
  }
}

// ---------------------------------------------------------------------------
// Flash-style causal attention (R7 form: setprio around MFMA clusters,
// defer-max THR=8). Persistent blocks + work-stealing, LDS-staged K/V,
// 2 lgkm-only barriers per s-block, register-double-buffered staging.
// (256,2): kernel needs ~180 regs/wave — forcing 3 waves/EU spills.
__global__ __launch_bounds__(256, 2) void attn(
    const __bf16* __restrict__ Q, const __bf16* __restrict__ K,
    const __bf16* __restrict__ Vt, __bf16* __restrict__ ctx,
    int* __restrict__ cnt) {
  constexpr float CSC = 0.12753139726f;  // log2(e)/sqrt(128)
  __shared__ __attribute__((aligned(16))) __bf16 Kls[64 * 128];   // [s][d]
  __shared__ __attribute__((aligned(16))) __bf16 Vls[128 * 64];   // [d][s]
  __shared__ __attribute__((aligned(16))) __bf16 Pls[4][32 * 64]; // [t][s]
  __shared__ int jobLds;

  const int tid = threadIdx.x;
  const int w = tid >> 6, l = tid & 63, quad = l >> 4, l16 = l & 15;

  const int krow = tid >> 4;                 // 0..15, +16 per pass
  const int kcol = tid & 15;
  const int kldsoff = ((kcol ^ krow) * 8);
  const int vrow = tid >> 3;                 // 0..31, +32 per pass
  const int vcol = tid & 7;
  const int vldsoff = ((vcol ^ (vrow & 7)) * 8);

  for (;;) {
    __syncthreads();
    if (tid == 0) jobLds = atomicAdd(cnt, 1);
    __syncthreads();
    const int j = jobLds;
    if (j >= 512) break;
    const int qt = 15 - (j >> 5);   // all qt=15 jobs first (LPT)
    const int bh = j & 31;
    const int t0w = qt * 128 + w * 32;
    const __bf16* Qbh = Q + (size_t)bh * TDIM * DHEAD;
    const __bf16* Kbh = K + (size_t)bh * TDIM * DHEAD;
    const __bf16* Vbh = Vt + (size_t)bh * TDIM * DHEAD;

    bf16x8 qf[2][4];
#pragma unroll
    for (int tt = 0; tt < 2; ++tt)
#pragma unroll
      for (int ks = 0; ks < 4; ++ks)
        qf[tt][ks] = *(const bf16x8*)(Qbh +
                     (size_t)(t0w + tt * 16 + l16) * DHEAD + ks * 32 + quad * 8);

    f32x4 oacc[8][2];
#pragma unroll
    for (int dt = 0; dt < 8; ++dt)
#pragma unroll
      for (int tt = 0; tt < 2; ++tt) oacc[dt][tt] = (f32x4){0.f, 0.f, 0.f, 0.f};
    float mrow[2] = {-1e30f, -1e30f};
    float lrow[2] = {0.f, 0.f};

    const int nsb = 2 * (qt + 1);

    // prefetch s-block 0 into regs
    bf16x8 kr[4], vr[4];
#pragma unroll
    for (int p = 0; p < 4; ++p)
      kr[p] = *(const bf16x8*)(Kbh + (size_t)(p * 16 + krow) * DHEAD + kcol * 8);
#pragma unroll
    for (int p = 0; p < 4; ++p)
      vr[p] = *(const bf16x8*)(Vbh + (size_t)(p * 32 + vrow) * TDIM + vcol * 8);

    for (int sb = 0; sb < nsb; ++sb) {
      const int s0 = sb * 64;
      BARRIER_LGKM();  // prior iteration's LDS reads complete
#pragma unroll
      for (int p = 0; p < 4; ++p)
        *(bf16x8*)&Kls[(p * 16 + krow) * 128 + kldsoff] = kr[p];
#pragma unroll
      for (int p = 0; p < 4; ++p)
        *(bf16x8*)&Vls[(p * 32 + vrow) * 64 + vldsoff] = vr[p];
      if (sb + 1 < nsb) {
        const int s1 = s0 + 64;
#pragma unroll
        for (int p = 0; p < 4; ++p)
          kr[p] = *(const bf16x8*)(Kbh + (size_t)(s1 + p * 16 + krow) * DHEAD +
                                   kcol * 8);
#pragma unroll
        for (int p = 0; p < 4; ++p)
          vr[p] = *(const bf16x8*)(Vbh + (size_t)(p * 32 + vrow) * TDIM + s1 +
                                   vcol * 8);
      }
      BARRIER_LGKM();  // staging visible; prefetch loads remain in flight
      if (s0 > t0w + 31) continue;  // fully masked for this wave

      // S^T = K.Q^T : D[row=s: quad*4+r][col=t: l16]
      f32x4 sacc[4][2];
#pragma unroll
      for (int st = 0; st < 4; ++st)
#pragma unroll
        for (int tt = 0; tt < 2; ++tt) sacc[st][tt] = (f32x4){0.f, 0.f, 0.f, 0.f};
      __builtin_amdgcn_s_setprio(1);
#pragma unroll
      for (int ks = 0; ks < 4; ++ks) {
        bf16x8 kf[4];
#pragma unroll
        for (int st = 0; st < 4; ++st)
          kf[st] = *(const bf16x8*)&Kls[(st * 16 + l16) * 128 +
                                        (((ks * 4 + quad) ^ l16) * 8)];
#pragma unroll
        for (int st = 0; st < 4; ++st)
#pragma unroll
          for (int tt = 0; tt < 2; ++tt)
            sacc[st][tt] = __builtin_amdgcn_mfma_f32_16x16x32_bf16(
                kf[st], qf[tt][ks], sacc[st][tt], 0, 0, 0);
      }
      __builtin_amdgcn_s_setprio(0);
      if (s0 + 63 > t0w) {  // causal mask near diagonal
#pragma unroll
        for (int st = 0; st < 4; ++st)
#pragma unroll
          for (int tt = 0; tt < 2; ++tt)
#pragma unroll
            for (int r = 0; r < 4; ++r) {
              const int s = s0 + st * 16 + quad * 4 + r;
              const int t = t0w + tt * 16 + l16;
              if (s > t) sacc[st][tt][r] = -1e30f;
            }
      }
      // online softmax per t-column (defer-max: rescale only when growth
      // exceeds 8 exp2-units; P stays bounded by 2^8)
#pragma unroll
      for (int tt = 0; tt < 2; ++tt) {
        float vm = -1e30f;
#pragma unroll
        for (int st = 0; st < 4; ++st)
#pragma unroll
          for (int r = 0; r < 4; ++r) vm = fmaxf(vm, sacc[st][tt][r]);
        vm = fmaxf(vm, __shfl_xor(vm, 16));
        vm = fmaxf(vm, __shfl_xor(vm, 32));
        if (__ballot((vm - mrow[tt]) * CSC > 8.0f)) {
          const float mn = fmaxf(mrow[tt], vm);
          const float alpha = exp2f((mrow[tt] - mn) * CSC);
          lrow[tt] *= alpha;
#pragma unroll
          for (int dt = 0; dt < 8; ++dt)
#pragma unroll
            for (int r = 0; r < 4; ++r) oacc[dt][tt][r] *= alpha;
          mrow[tt] = mn;
        }
        const float mcur = mrow[tt];
        float rs = 0.f;
#pragma unroll
        for (int st = 0; st < 4; ++st) {
          const float p0 = exp2f((sacc[st][tt][0] - mcur) * CSC);
          const float p1 = exp2f((sacc[st][tt][1] - mcur) * CSC);
          const float p2 = exp2f((sacc[st][tt][2] - mcur) * CSC);
          const float p3 = exp2f((sacc[st][tt][3] - mcur) * CSC);
          rs += (p0 + p1) + (p2 + p3);
          u32x2 pk = {pk2bf_trunc(p0, p1), pk2bf_trunc(p2, p3)};
          *(u32x2*)&Pls[w][(tt * 16 + l16) * 64 +
                           (((st * 2 + (quad >> 1)) ^ (l16 & 7)) * 8) +
                           (quad & 1) * 4] = pk;
        }
        rs += __shfl_xor(rs, 16);
        rs += __shfl_xor(rs, 32);
        lrow[tt] += rs;
      }
      // intra-wave P write->read ordering (wave-private region, no barrier)
      asm volatile("s_waitcnt lgkmcnt(0)" ::: "memory");
      // O^T += V^T.P^T : D[row=d][col=t]
      __builtin_amdgcn_s_setprio(1);
#pragma unroll
      for (int ks = 0; ks < 2; ++ks) {
        bf16x8 pf[2];
#pragma unroll
        for (int tt = 0; tt < 2; ++tt)
          pf[tt] = *(const bf16x8*)&Pls[w][(tt * 16 + l16) * 64 +
                                           (((ks * 4 + quad) ^ (l16 & 7)) * 8)];
#pragma unroll
        for (int dt = 0; dt < 8; ++dt) {
          const bf16x8 vf =
              *(const bf16x8*)&Vls[(dt * 16 + l16) * 64 +
                                   (((ks * 4 + quad) ^ (l16 & 7)) * 8)];
#pragma unroll
          for (int tt = 0; tt < 2; ++tt)
            oacc[dt][tt] = __builtin_amdgcn_mfma_f32_16x16x32_bf16(
                vf, pf[tt], oacc[dt][tt], 0, 0, 0);
        }
      }
      __builtin_amdgcn_s_setprio(0);
    }

    // epilogue: O^T[d][t]/l -> ctx[b][t][h*128+d], bf16x4 stores
    const int b = bh >> 4, h = bh & 15;
#pragma unroll
    for (int tt = 0; tt < 2; ++tt) {
      const float rinv = 1.0f / lrow[tt];
      const int t = t0w + tt * 16 + l16;
      __bf16* cp = ctx + ((size_t)(b * TDIM + t)) * CDIM + h * DHEAD;
#pragma unroll
      for (int dt = 0; dt < 8; ++dt) {
        bf16x4v v4;
#pragma unroll
        for (int r = 0; r < 4; ++r) v4[r] = f2bf(oacc[dt][tt][r] * rinv);
        *(bf16x4*)&cp[dt * 16 + quad * 4] = v4;
      }
    }
  }
}

// ---------------------------------------------------------------------------
extern "C" void kernel_launch(void* const* d_in, const int* in_sizes, int n_in,
                              void* d_out, int out_size, void* d_ws,
                              size_t ws_size, hipStream_t stream) {
  const void* src = d_in[0];
  const void* Wq = d_in[1];
  const void* bq = d_in[2];
  const void* Wk = d_in[3];
  const void* bk = d_in[4];
  const void* Wv = d_in[5];
  const void* bv = d_in[6];
  const void* Wo = d_in[7];
  const void* bo = d_in[8];

  char* wsb = (char*)d_ws;
  int* cnt = (int*)(wsb + 128);           // +128 (work-steal counter)
  __bf16* srcbf = (__bf16*)(wsb + 256);
  __bf16* wqt = srcbf + XSZ;              // q,k,v,o transposed, contiguous
  __bf16* wot = wqt + 3 * WSZ;
  __bf16* qb = wot + WSZ;                 // [B*NH][T][D]
  __bf16* kb = qb + XSZ;                  // [B*NH][T][D]
  __bf16* vtb = kb + XSZ;                 // [B*NH][D][T]
  float* biasf = (float*)(vtb + XSZ);     // 4 x 2048 f32
  __bf16* ctx = srcbf;                    // reuse (src consumed by then)

  // fused prologue: src cvt (4096) + bias cvt/cnt-zero (32) + wt transpose
  // (4096) = 8224 blocks, one launch.
  prologue<<<8224, 256, 0, stream>>>(src, srcbf, (int)(XSZ / 8), bq, bk, bv,
                                     bo, biasf, Wq, Wk, Wv, Wo, wqt, cnt);
  // fused QKV: M=4096, N=6144, BM=128 x BN=256 -> 32x24 = 768 blocks
  // (now 2 blocks/CU resident -> 1.5 scheduling rounds)
  gemmring<0><<<768, 512, 0, stream>>>(srcbf, wqt, biasf, qb, kb, vtb,
                                       nullptr, nullptr);
  attn<<<512, 256, 0, stream>>>(qb, kb, vtb, ctx, cnt);
  // out-proj: M=4096, N=2048 -> 32x8 = 256 blocks
  gemmring<1><<<256, 512, 0, stream>>>(ctx, wot, biasf + 6144, nullptr,
                                       nullptr, nullptr, (const unsigned*)src,
                                       d_out);
}